// Round 5
// baseline (883.288 us; speedup 1.0000x reference)
//
#include <hip/hip_runtime.h>
#include <math.h>

#define N_NODES 100000
#define N_EDGES 1600000
#define LN_EPS 1e-5f
#define NORM_EPS 1e-12f
#define SCAN_TILE 1024
#define N_TILES ((N_NODES + SCAN_TILE - 1) / SCAN_TILE)   // 98
#define ROWS_PER_BLOCK 32
#define GEMM_BLOCKS (N_NODES / ROWS_PER_BLOCK)            // 3125, exact

// bf16 helpers (round-to-nearest-even)
__device__ __forceinline__ unsigned short f2bf(float f) {
    unsigned int u = __float_as_uint(f);
    u += 0x7FFFu + ((u >> 16) & 1u);
    return (unsigned short)(u >> 16);
}
__device__ __forceinline__ float bf2f(unsigned short h) {
    return __uint_as_float(((unsigned int)h) << 16);
}

// ---------------------------------------------------------------------------
// K1: h = x @ W^T + b (N x 64) -> bf16; per-node attn scores; fused edge
// count (2 edges/thread, grid covers E exactly, atomics AFTER the k-loop so
// no barrier drains them).
// Register-blocked: 8 rows/wave in acc[8]; per 4-k chunk: 4 scalar WL reads
// (stride 65 -> 2-way, free) + 8 float4 broadcast xs reads + 32 FMAs.
// ---------------------------------------------------------------------------
__global__ __launch_bounds__(256, 4) void k_gemm(
    const float* __restrict__ x, const float* __restrict__ W,
    const float* __restrict__ b, const float* __restrict__ a,
    const int* __restrict__ ei, int* __restrict__ counts,
    unsigned short* __restrict__ h16,
    float* __restrict__ s_src, float* __restrict__ s_dst)
{
    __shared__ float WL[64 * 65];                 // WL[k*65 + c] = W[c][k]
    __shared__ float xs[ROWS_PER_BLOCK * 64];
    const int tid  = threadIdx.x;
    const int lane = tid & 63;
    const int wv   = tid >> 6;

    // stage W transposed: scalar coalesced reads, conflict-free writes
    for (int idx = tid; idx < 64 * 64; idx += 256)
        WL[(idx & 63) * 65 + (idx >> 6)] = W[idx];

    const int row0 = blockIdx.x * ROWS_PER_BLOCK;
    for (int idx = tid * 4; idx < ROWS_PER_BLOCK * 64; idx += 256 * 4)
        *(float4*)(xs + idx) = *(const float4*)(x + (size_t)row0 * 64 + idx);
    __syncthreads();

    const float bias = b[lane];
    float acc[8];
    #pragma unroll
    for (int r = 0; r < 8; ++r) acc[r] = bias;

    const int rbase = wv * 8;
    #pragma unroll
    for (int kk = 0; kk < 16; ++kk) {
        const float w0 = WL[(4 * kk + 0) * 65 + lane];
        const float w1 = WL[(4 * kk + 1) * 65 + lane];
        const float w2 = WL[(4 * kk + 2) * 65 + lane];
        const float w3 = WL[(4 * kk + 3) * 65 + lane];
        #pragma unroll
        for (int r = 0; r < 8; ++r) {
            const float4 xr = *(const float4*)(xs + (rbase + r) * 64 + 4 * kk);
            acc[r] += xr.x * w0 + xr.y * w1 + xr.z * w2 + xr.w * w3;
        }
    }

    // fused out-degree count: no __syncthreads after this point
    {
        const int e0 = blockIdx.x * 256 + tid;
        atomicAdd(&counts[ei[e0]], 1);
        atomicAdd(&counts[ei[e0 + GEMM_BLOCKS * 256]], 1);
    }

    const float asrc = a[(lane >> 3) * 16 + (lane & 7)];
    const float adst = a[(lane >> 3) * 16 + 8 + (lane & 7)];
    #pragma unroll
    for (int r = 0; r < 8; ++r) {
        const int row = row0 + rbase + r;
        const float v = acc[r];
        h16[(size_t)row * 64 + lane] = f2bf(v);
        float p = v * asrc, q = v * adst;
        p += __shfl_xor(p, 1);  q += __shfl_xor(q, 1);
        p += __shfl_xor(p, 2);  q += __shfl_xor(q, 2);
        p += __shfl_xor(p, 4);  q += __shfl_xor(q, 4);
        if ((lane & 7) == 0) {
            s_src[row * 8 + (lane >> 3)] = p;
            s_dst[row * 8 + (lane >> 3)] = q;
        }
    }
}

// ---------------------------------------------------------------------------
// Scan stage 1: per-tile (1024) exclusive scan + tile totals.
// ---------------------------------------------------------------------------
__global__ __launch_bounds__(1024) void k_scan1(
    const int* __restrict__ counts, int* __restrict__ row_ptr,
    int* __restrict__ blksum)
{
    __shared__ int wsum[16];
    const int tid = threadIdx.x, lane = tid & 63, wv = tid >> 6;
    const int i = blockIdx.x * SCAN_TILE + tid;
    int v = (i < N_NODES) ? counts[i] : 0;
    int sc = v;
    #pragma unroll
    for (int off = 1; off < 64; off <<= 1) {
        int t = __shfl_up(sc, off);
        if (lane >= off) sc += t;
    }
    if (lane == 63) wsum[wv] = sc;
    __syncthreads();
    if (tid < 16) {
        int ws = wsum[tid];
        #pragma unroll
        for (int off = 1; off < 16; off <<= 1) {
            int t = __shfl_up(ws, off);
            if (tid >= off) ws += t;
        }
        wsum[tid] = ws;
    }
    __syncthreads();
    const int pref = wv ? wsum[wv - 1] : 0;
    if (i < N_NODES) row_ptr[i] = pref + sc - v;   // tile-local exclusive
    if (tid == 0) blksum[blockIdx.x] = wsum[15];
}

// ---------------------------------------------------------------------------
// Scan stages 2+3 fused: redundant 98-element scan per block, add-back,
// cursor init.
// ---------------------------------------------------------------------------
__global__ __launch_bounds__(256) void k_scan23(
    int* __restrict__ row_ptr, const int* __restrict__ blksum,
    int* __restrict__ cursor)
{
    __shared__ int spref[N_TILES];
    const int tid = threadIdx.x;
    if (tid < 64) {
        int v0 = (tid < N_TILES) ? blksum[tid] : 0;
        int s0 = v0;
        #pragma unroll
        for (int off = 1; off < 64; off <<= 1) {
            int t = __shfl_up(s0, off);
            if (tid >= off) s0 += t;
        }
        if (tid < N_TILES) spref[tid] = s0 - v0;
        int carry = __shfl(s0, 63);
        int i2 = 64 + tid;
        int v1 = (i2 < N_TILES) ? blksum[i2] : 0;
        int s1 = v1;
        #pragma unroll
        for (int off = 1; off < 64; off <<= 1) {
            int t = __shfl_up(s1, off);
            if (tid >= off) s1 += t;
        }
        if (i2 < N_TILES) spref[i2] = carry + s1 - v1;
    }
    __syncthreads();
    const int i = blockIdx.x * 256 + tid;
    if (i < N_NODES) {
        int r = row_ptr[i] + spref[i >> 10];
        row_ptr[i] = r;
        cursor[i] = r;
    }
    if (i == 0) row_ptr[N_NODES] = N_EDGES;
}

// ---------------------------------------------------------------------------
// Fill + alpha: one THREAD per edge; scatter dst, compute 8-head softmax once.
// ---------------------------------------------------------------------------
__global__ __launch_bounds__(256) void k_fill_alpha(
    const int* __restrict__ ei, int* __restrict__ cursor,
    const float* __restrict__ s_src, const float* __restrict__ s_dst,
    int* __restrict__ dst_sorted, float* __restrict__ alpha8)
{
    const int e = blockIdx.x * 256 + threadIdx.x;
    if (e >= N_EDGES) return;
    const int src = ei[e];
    const int dst = ei[N_EDGES + e];
    const int slot = atomicAdd(&cursor[src], 1);
    dst_sorted[slot] = dst;

    const float4 a0 = *(const float4*)(s_src + (size_t)src * 8);
    const float4 a1 = *(const float4*)(s_src + (size_t)src * 8 + 4);
    const float4 b0 = *(const float4*)(s_dst + (size_t)dst * 8);
    const float4 b1 = *(const float4*)(s_dst + (size_t)dst * 8 + 4);
    float sc[8] = {a0.x + b0.x, a0.y + b0.y, a0.z + b0.z, a0.w + b0.w,
                   a1.x + b1.x, a1.y + b1.y, a1.z + b1.z, a1.w + b1.w};
    float m = -1e30f;
    #pragma unroll
    for (int h = 0; h < 8; ++h) {
        sc[h] = (sc[h] >= 0.f) ? sc[h] : 0.2f * sc[h];
        m = fmaxf(m, sc[h]);
    }
    float sum = 0.f;
    #pragma unroll
    for (int h = 0; h < 8; ++h) { sc[h] = __expf(sc[h] - m); sum += sc[h]; }
    const float inv = 1.f / sum;
    float4 o0 = make_float4(sc[0] * inv, sc[1] * inv, sc[2] * inv, sc[3] * inv);
    float4 o1 = make_float4(sc[4] * inv, sc[5] * inv, sc[6] * inv, sc[7] * inv);
    *(float4*)(alpha8 + (size_t)slot * 8)     = o0;
    *(float4*)(alpha8 + (size_t)slot * 8 + 4) = o1;
}

// ---------------------------------------------------------------------------
// Gather + epilogue: one wave per node; slim inner loop (alpha precomputed).
// ---------------------------------------------------------------------------
__global__ __launch_bounds__(256) void k_gather(
    const int* __restrict__ row_ptr, const int* __restrict__ dst_sorted,
    const float* __restrict__ alpha8, const unsigned short* __restrict__ h16,
    const float* __restrict__ x, const float* __restrict__ ln_scale,
    const float* __restrict__ ln_bias, float* __restrict__ out)
{
    const int i = blockIdx.x * 4 + (threadIdx.x >> 6);
    if (i >= N_NODES) return;
    const int lane = threadIdx.x & 63;
    const int head = lane >> 3;

    const int beg = row_ptr[i];
    const int end = row_ptr[i + 1];
    const float xres = x[(size_t)i * 64 + lane];

    float acc = 0.f;
    int e = beg;
    for (; e + 3 < end; e += 4) {
        const int d0 = dst_sorted[e];
        const int d1 = dst_sorted[e + 1];
        const int d2 = dst_sorted[e + 2];
        const int d3 = dst_sorted[e + 3];
        const float al0 = alpha8[(size_t)(e + 0) * 8 + head];
        const float al1 = alpha8[(size_t)(e + 1) * 8 + head];
        const float al2 = alpha8[(size_t)(e + 2) * 8 + head];
        const float al3 = alpha8[(size_t)(e + 3) * 8 + head];
        const float h0 = bf2f(h16[(size_t)d0 * 64 + lane]);
        const float h1 = bf2f(h16[(size_t)d1 * 64 + lane]);
        const float h2 = bf2f(h16[(size_t)d2 * 64 + lane]);
        const float h3 = bf2f(h16[(size_t)d3 * 64 + lane]);
        acc += al0 * h0 + al1 * h1 + al2 * h2 + al3 * h3;
    }
    for (; e < end; ++e)
        acc += alpha8[(size_t)e * 8 + head] *
               bf2f(h16[(size_t)dst_sorted[e] * 64 + lane]);

    // epilogue: residual + LayerNorm + L2 normalize
    float v = acc + xres;
    float s = v;
    #pragma unroll
    for (int off = 1; off < 64; off <<= 1) s += __shfl_xor(s, off);
    const float mu = s * (1.f / 64.f);
    const float d = v - mu;
    float vs = d * d;
    #pragma unroll
    for (int off = 1; off < 64; off <<= 1) vs += __shfl_xor(vs, off);
    const float var = vs * (1.f / 64.f);
    float y = d * rsqrtf(var + LN_EPS) * ln_scale[lane] + ln_bias[lane];
    float ss = y * y;
    #pragma unroll
    for (int off = 1; off < 64; off <<= 1) ss += __shfl_xor(ss, off);
    const float norm = sqrtf(ss);
    out[(size_t)i * 64 + lane] = y / fmaxf(norm, NORM_EPS);
}

// ---------------------------------------------------------------------------
extern "C" void kernel_launch(void* const* d_in, const int* in_sizes, int n_in,
                              void* d_out, int out_size, void* d_ws, size_t ws_size,
                              hipStream_t stream)
{
    const float* x        = (const float*)d_in[0];
    const int*   ei       = (const int*)d_in[1];
    const float* W        = (const float*)d_in[2];
    const float* b        = (const float*)d_in[3];
    const float* a        = (const float*)d_in[4];
    const float* ln_scale = (const float*)d_in[5];
    const float* ln_bias  = (const float*)d_in[6];
    float* out = (float*)d_out;

    char* ws = (char*)d_ws;
    size_t off = 0;
    auto alloc = [&](size_t bytes) {
        void* p = ws + off;
        off = (off + bytes + 255) & ~(size_t)255;
        return p;
    };
    unsigned short* h16 = (unsigned short*)alloc((size_t)N_NODES * 64 * 2);
    float* s_src      = (float*)alloc((size_t)N_NODES * 8 * 4);
    float* s_dst      = (float*)alloc((size_t)N_NODES * 8 * 4);
    int*   counts     = (int*)  alloc((size_t)N_NODES * 4);
    int*   row_ptr    = (int*)  alloc((size_t)(N_NODES + 1) * 4);
    int*   cursor     = (int*)  alloc((size_t)N_NODES * 4);
    int*   blksum     = (int*)  alloc((size_t)N_TILES * 4);
    int*   dst_sorted = (int*)  alloc((size_t)N_EDGES * 4);
    float* alpha8     = (float*)alloc((size_t)N_EDGES * 8 * 4);

    hipMemsetAsync(counts, 0, (size_t)N_NODES * 4, stream);

    k_gemm      <<<GEMM_BLOCKS, 256, 0, stream>>>(x, W, b, a, ei, counts,
                                                  h16, s_src, s_dst);
    k_scan1     <<<N_TILES, 1024, 0, stream>>>(counts, row_ptr, blksum);
    k_scan23    <<<(N_NODES + 255) / 256, 256, 0, stream>>>(row_ptr, blksum, cursor);
    k_fill_alpha<<<(N_EDGES + 255) / 256, 256, 0, stream>>>(ei, cursor, s_src, s_dst,
                                                            dst_sorted, alpha8);
    k_gather    <<<(N_NODES + 3) / 4,     256, 0, stream>>>(row_ptr, dst_sorted,
                                                            alpha8, h16, x,
                                                            ln_scale, ln_bias, out);
}

// Round 6
// 692.475 us; speedup vs baseline: 1.2756x; 1.2756x over previous
//
#include <hip/hip_runtime.h>
#include <math.h>

#define N_NODES 100000
#define N_EDGES 1600000
#define LN_EPS 1e-5f
#define NORM_EPS 1e-12f
#define SCAN_TILE 1024
#define N_TILES ((N_NODES + SCAN_TILE - 1) / SCAN_TILE)   // 98
#define ROWS_PER_BLOCK 32
#define GEMM_BLOCKS (N_NODES / ROWS_PER_BLOCK)            // 3125, exact

// bf16 helpers (round-to-nearest-even)
__device__ __forceinline__ unsigned short f2bf(float f) {
    unsigned int u = __float_as_uint(f);
    u += 0x7FFFu + ((u >> 16) & 1u);
    return (unsigned short)(u >> 16);
}
__device__ __forceinline__ float bf2f(unsigned short h) {
    return __uint_as_float(((unsigned int)h) << 16);
}

// ---------------------------------------------------------------------------
// K1: h = x @ W^T + b (N x 64) -> bf16; per-node attn scores; fused edge
// count (2 edges/thread, atomics AFTER the k-loop: no barrier drains them).
// Register-blocked: 8 rows/wave in acc[8].
// __launch_bounds__(256, 2): min-waves=2 -> VGPR cap 256.  NEVER ask for 4:
// R5 measured the compiler squeezing to 64 VGPRs and spilling acc[] to
// scratch -> 2.03 GB HBM traffic, 617 us (VALUBusy 3%).
// ---------------------------------------------------------------------------
__global__ __launch_bounds__(256, 2) void k_gemm(
    const float* __restrict__ x, const float* __restrict__ W,
    const float* __restrict__ b, const float* __restrict__ a,
    const int* __restrict__ ei, int* __restrict__ counts,
    unsigned short* __restrict__ h16,
    float* __restrict__ s_src, float* __restrict__ s_dst)
{
    __shared__ float WL[64 * 65];                 // WL[k*65 + c] = W[c][k]
    __shared__ float xs[ROWS_PER_BLOCK * 64];
    const int tid  = threadIdx.x;
    const int lane = tid & 63;
    const int wv   = tid >> 6;

    // stage W transposed: scalar coalesced reads, conflict-free writes
    for (int idx = tid; idx < 64 * 64; idx += 256)
        WL[(idx & 63) * 65 + (idx >> 6)] = W[idx];

    const int row0 = blockIdx.x * ROWS_PER_BLOCK;
    for (int idx = tid * 4; idx < ROWS_PER_BLOCK * 64; idx += 256 * 4)
        *(float4*)(xs + idx) = *(const float4*)(x + (size_t)row0 * 64 + idx);
    __syncthreads();

    const float bias = b[lane];
    float acc[8];
    #pragma unroll
    for (int r = 0; r < 8; ++r) acc[r] = bias;

    const int rbase = wv * 8;
    #pragma unroll
    for (int kk = 0; kk < 16; ++kk) {
        const float w0 = WL[(4 * kk + 0) * 65 + lane];
        const float w1 = WL[(4 * kk + 1) * 65 + lane];
        const float w2 = WL[(4 * kk + 2) * 65 + lane];
        const float w3 = WL[(4 * kk + 3) * 65 + lane];
        #pragma unroll
        for (int r = 0; r < 8; ++r) {
            const float4 xr = *(const float4*)(xs + (rbase + r) * 64 + 4 * kk);
            acc[r] += xr.x * w0 + xr.y * w1 + xr.z * w2 + xr.w * w3;
        }
    }

    // fused out-degree count: no __syncthreads after this point
    {
        const int e0 = blockIdx.x * 256 + tid;
        atomicAdd(&counts[ei[e0]], 1);
        atomicAdd(&counts[ei[e0 + GEMM_BLOCKS * 256]], 1);
    }

    const float asrc = a[(lane >> 3) * 16 + (lane & 7)];
    const float adst = a[(lane >> 3) * 16 + 8 + (lane & 7)];
    #pragma unroll
    for (int r = 0; r < 8; ++r) {
        const int row = row0 + rbase + r;
        const float v = acc[r];
        h16[(size_t)row * 64 + lane] = f2bf(v);
        float p = v * asrc, q = v * adst;
        p += __shfl_xor(p, 1);  q += __shfl_xor(q, 1);
        p += __shfl_xor(p, 2);  q += __shfl_xor(q, 2);
        p += __shfl_xor(p, 4);  q += __shfl_xor(q, 4);
        if ((lane & 7) == 0) {
            s_src[row * 8 + (lane >> 3)] = p;
            s_dst[row * 8 + (lane >> 3)] = q;
        }
    }
}

// ---------------------------------------------------------------------------
// Scan stage 1: per-tile (1024) exclusive scan + tile totals.
// ---------------------------------------------------------------------------
__global__ __launch_bounds__(1024) void k_scan1(
    const int* __restrict__ counts, int* __restrict__ row_ptr,
    int* __restrict__ blksum)
{
    __shared__ int wsum[16];
    const int tid = threadIdx.x, lane = tid & 63, wv = tid >> 6;
    const int i = blockIdx.x * SCAN_TILE + tid;
    int v = (i < N_NODES) ? counts[i] : 0;
    int sc = v;
    #pragma unroll
    for (int off = 1; off < 64; off <<= 1) {
        int t = __shfl_up(sc, off);
        if (lane >= off) sc += t;
    }
    if (lane == 63) wsum[wv] = sc;
    __syncthreads();
    if (tid < 16) {
        int ws = wsum[tid];
        #pragma unroll
        for (int off = 1; off < 16; off <<= 1) {
            int t = __shfl_up(ws, off);
            if (tid >= off) ws += t;
        }
        wsum[tid] = ws;
    }
    __syncthreads();
    const int pref = wv ? wsum[wv - 1] : 0;
    if (i < N_NODES) row_ptr[i] = pref + sc - v;   // tile-local exclusive
    if (tid == 0) blksum[blockIdx.x] = wsum[15];
}

// ---------------------------------------------------------------------------
// Scan stages 2+3 fused: redundant 98-element scan per block, add-back,
// cursor init.
// ---------------------------------------------------------------------------
__global__ __launch_bounds__(256) void k_scan23(
    int* __restrict__ row_ptr, const int* __restrict__ blksum,
    int* __restrict__ cursor)
{
    __shared__ int spref[N_TILES];
    const int tid = threadIdx.x;
    if (tid < 64) {
        int v0 = (tid < N_TILES) ? blksum[tid] : 0;
        int s0 = v0;
        #pragma unroll
        for (int off = 1; off < 64; off <<= 1) {
            int t = __shfl_up(s0, off);
            if (tid >= off) s0 += t;
        }
        if (tid < N_TILES) spref[tid] = s0 - v0;
        int carry = __shfl(s0, 63);
        int i2 = 64 + tid;
        int v1 = (i2 < N_TILES) ? blksum[i2] : 0;
        int s1 = v1;
        #pragma unroll
        for (int off = 1; off < 64; off <<= 1) {
            int t = __shfl_up(s1, off);
            if (tid >= off) s1 += t;
        }
        if (i2 < N_TILES) spref[i2] = carry + s1 - v1;
    }
    __syncthreads();
    const int i = blockIdx.x * 256 + tid;
    if (i < N_NODES) {
        int r = row_ptr[i] + spref[i >> 10];
        row_ptr[i] = r;
        cursor[i] = r;
    }
    if (i == 0) row_ptr[N_NODES] = N_EDGES;
}

// ---------------------------------------------------------------------------
// Fill + alpha: one THREAD per edge; scatter dst, compute 8-head softmax once.
// ---------------------------------------------------------------------------
__global__ __launch_bounds__(256) void k_fill_alpha(
    const int* __restrict__ ei, int* __restrict__ cursor,
    const float* __restrict__ s_src, const float* __restrict__ s_dst,
    int* __restrict__ dst_sorted, float* __restrict__ alpha8)
{
    const int e = blockIdx.x * 256 + threadIdx.x;
    if (e >= N_EDGES) return;
    const int src = ei[e];
    const int dst = ei[N_EDGES + e];
    const int slot = atomicAdd(&cursor[src], 1);
    dst_sorted[slot] = dst;

    const float4 a0 = *(const float4*)(s_src + (size_t)src * 8);
    const float4 a1 = *(const float4*)(s_src + (size_t)src * 8 + 4);
    const float4 b0 = *(const float4*)(s_dst + (size_t)dst * 8);
    const float4 b1 = *(const float4*)(s_dst + (size_t)dst * 8 + 4);
    float sc[8] = {a0.x + b0.x, a0.y + b0.y, a0.z + b0.z, a0.w + b0.w,
                   a1.x + b1.x, a1.y + b1.y, a1.z + b1.z, a1.w + b1.w};
    float m = -1e30f;
    #pragma unroll
    for (int h = 0; h < 8; ++h) {
        sc[h] = (sc[h] >= 0.f) ? sc[h] : 0.2f * sc[h];
        m = fmaxf(m, sc[h]);
    }
    float sum = 0.f;
    #pragma unroll
    for (int h = 0; h < 8; ++h) { sc[h] = __expf(sc[h] - m); sum += sc[h]; }
    const float inv = 1.f / sum;
    float4 o0 = make_float4(sc[0] * inv, sc[1] * inv, sc[2] * inv, sc[3] * inv);
    float4 o1 = make_float4(sc[4] * inv, sc[5] * inv, sc[6] * inv, sc[7] * inv);
    *(float4*)(alpha8 + (size_t)slot * 8)     = o0;
    *(float4*)(alpha8 + (size_t)slot * 8 + 4) = o1;
}

// ---------------------------------------------------------------------------
// Gather + epilogue: one wave per node; slim inner loop (alpha precomputed).
// ---------------------------------------------------------------------------
__global__ __launch_bounds__(256) void k_gather(
    const int* __restrict__ row_ptr, const int* __restrict__ dst_sorted,
    const float* __restrict__ alpha8, const unsigned short* __restrict__ h16,
    const float* __restrict__ x, const float* __restrict__ ln_scale,
    const float* __restrict__ ln_bias, float* __restrict__ out)
{
    const int i = blockIdx.x * 4 + (threadIdx.x >> 6);
    if (i >= N_NODES) return;
    const int lane = threadIdx.x & 63;
    const int head = lane >> 3;

    const int beg = row_ptr[i];
    const int end = row_ptr[i + 1];
    const float xres = x[(size_t)i * 64 + lane];

    float acc = 0.f;
    int e = beg;
    for (; e + 3 < end; e += 4) {
        const int d0 = dst_sorted[e];
        const int d1 = dst_sorted[e + 1];
        const int d2 = dst_sorted[e + 2];
        const int d3 = dst_sorted[e + 3];
        const float al0 = alpha8[(size_t)(e + 0) * 8 + head];
        const float al1 = alpha8[(size_t)(e + 1) * 8 + head];
        const float al2 = alpha8[(size_t)(e + 2) * 8 + head];
        const float al3 = alpha8[(size_t)(e + 3) * 8 + head];
        const float h0 = bf2f(h16[(size_t)d0 * 64 + lane]);
        const float h1 = bf2f(h16[(size_t)d1 * 64 + lane]);
        const float h2 = bf2f(h16[(size_t)d2 * 64 + lane]);
        const float h3 = bf2f(h16[(size_t)d3 * 64 + lane]);
        acc += al0 * h0 + al1 * h1 + al2 * h2 + al3 * h3;
    }
    for (; e < end; ++e)
        acc += alpha8[(size_t)e * 8 + head] *
               bf2f(h16[(size_t)dst_sorted[e] * 64 + lane]);

    // epilogue: residual + LayerNorm + L2 normalize
    float v = acc + xres;
    float s = v;
    #pragma unroll
    for (int off = 1; off < 64; off <<= 1) s += __shfl_xor(s, off);
    const float mu = s * (1.f / 64.f);
    const float d = v - mu;
    float vs = d * d;
    #pragma unroll
    for (int off = 1; off < 64; off <<= 1) vs += __shfl_xor(vs, off);
    const float var = vs * (1.f / 64.f);
    float y = d * rsqrtf(var + LN_EPS) * ln_scale[lane] + ln_bias[lane];
    float ss = y * y;
    #pragma unroll
    for (int off = 1; off < 64; off <<= 1) ss += __shfl_xor(ss, off);
    const float norm = sqrtf(ss);
    out[(size_t)i * 64 + lane] = y / fmaxf(norm, NORM_EPS);
}

// ---------------------------------------------------------------------------
extern "C" void kernel_launch(void* const* d_in, const int* in_sizes, int n_in,
                              void* d_out, int out_size, void* d_ws, size_t ws_size,
                              hipStream_t stream)
{
    const float* x        = (const float*)d_in[0];
    const int*   ei       = (const int*)d_in[1];
    const float* W        = (const float*)d_in[2];
    const float* b        = (const float*)d_in[3];
    const float* a        = (const float*)d_in[4];
    const float* ln_scale = (const float*)d_in[5];
    const float* ln_bias  = (const float*)d_in[6];
    float* out = (float*)d_out;

    char* ws = (char*)d_ws;
    size_t off = 0;
    auto alloc = [&](size_t bytes) {
        void* p = ws + off;
        off = (off + bytes + 255) & ~(size_t)255;
        return p;
    };
    unsigned short* h16 = (unsigned short*)alloc((size_t)N_NODES * 64 * 2);
    float* s_src      = (float*)alloc((size_t)N_NODES * 8 * 4);
    float* s_dst      = (float*)alloc((size_t)N_NODES * 8 * 4);
    int*   counts     = (int*)  alloc((size_t)N_NODES * 4);
    int*   row_ptr    = (int*)  alloc((size_t)(N_NODES + 1) * 4);
    int*   cursor     = (int*)  alloc((size_t)N_NODES * 4);
    int*   blksum     = (int*)  alloc((size_t)N_TILES * 4);
    int*   dst_sorted = (int*)  alloc((size_t)N_EDGES * 4);
    float* alpha8     = (float*)alloc((size_t)N_EDGES * 8 * 4);

    hipMemsetAsync(counts, 0, (size_t)N_NODES * 4, stream);

    k_gemm      <<<GEMM_BLOCKS, 256, 0, stream>>>(x, W, b, a, ei, counts,
                                                  h16, s_src, s_dst);
    k_scan1     <<<N_TILES, 1024, 0, stream>>>(counts, row_ptr, blksum);
    k_scan23    <<<(N_NODES + 255) / 256, 256, 0, stream>>>(row_ptr, blksum, cursor);
    k_fill_alpha<<<(N_EDGES + 255) / 256, 256, 0, stream>>>(ei, cursor, s_src, s_dst,
                                                            dst_sorted, alpha8);
    k_gather    <<<(N_NODES + 3) / 4,     256, 0, stream>>>(row_ptr, dst_sorted,
                                                            alpha8, h16, x,
                                                            ln_scale, ln_bias, out);
}

// Round 7
// 333.233 us; speedup vs baseline: 2.6507x; 2.0780x over previous
//
#include <hip/hip_runtime.h>
#include <math.h>

#define N_NODES 100000
#define N_EDGES 1600000
#define LN_EPS 1e-5f
#define NORM_EPS 1e-12f
#define SCAN_TILE 1024
#define N_TILES ((N_NODES + SCAN_TILE - 1) / SCAN_TILE)   // 98
#define ROWS_PER_BLOCK 32
#define GEMM_BLOCKS (N_NODES / ROWS_PER_BLOCK)            // 3125, exact
#define WSTRIDE 66   // dword stride: even (b64-aligned) and 2c+k -> 2-way banks (free)

// bf16 helpers (round-to-nearest-even)
__device__ __forceinline__ unsigned short f2bf(float f) {
    unsigned int u = __float_as_uint(f);
    u += 0x7FFFu + ((u >> 16) & 1u);
    return (unsigned short)(u >> 16);
}
__device__ __forceinline__ float bf2f(unsigned short h) {
    return __uint_as_float(((unsigned int)h) << 16);
}

// ---------------------------------------------------------------------------
// K1: h = x @ W^T + b (N x 64) -> bf16; per-node attn scores; fused edge
// count (2 edges/thread, atomics AFTER the k-loop).
// Lane = output column c.  W row c in LDS at stride 66 (b64 reads, 2-way =
// free).  x quads read as wave-uniform b128 broadcasts.  8 rows/wave.
// K-LOOP IS DELIBERATELY NOT UNROLLED (#pragma unroll 1): R5/R6 measured the
// fully-unrolled float4 version spilling acc[] to scratch (2.0 GB / 0.95 GB
// HBM writes, VALUBusy 3% / 0.1%) at ANY VGPR budget the allocator picked.
// Rolled loop keeps the live set ~30 VGPRs -> spill-proof. No min-waves hint.
// ---------------------------------------------------------------------------
__global__ __launch_bounds__(256) void k_gemm(
    const float* __restrict__ x, const float* __restrict__ W,
    const float* __restrict__ b, const float* __restrict__ a,
    const int* __restrict__ ei, int* __restrict__ counts,
    unsigned short* __restrict__ h16,
    float* __restrict__ s_src, float* __restrict__ s_dst)
{
    __shared__ float WL[64 * WSTRIDE];            // WL[c*66 + k] = W[c][k]
    __shared__ float xs[ROWS_PER_BLOCK * 64];
    const int tid  = threadIdx.x;
    const int lane = tid & 63;
    const int wv   = tid >> 6;

    // stage W: float4 global reads, 4 scalar LDS writes (banks 2c+k+j, 2-way)
    for (int idx = tid * 4; idx < 64 * 64; idx += 256 * 4) {
        const float4 w = *(const float4*)(W + idx);
        const int c = idx >> 6, k = idx & 63;
        WL[c * WSTRIDE + k + 0] = w.x;
        WL[c * WSTRIDE + k + 1] = w.y;
        WL[c * WSTRIDE + k + 2] = w.z;
        WL[c * WSTRIDE + k + 3] = w.w;
    }
    const int row0 = blockIdx.x * ROWS_PER_BLOCK;
    for (int idx = tid * 4; idx < ROWS_PER_BLOCK * 64; idx += 256 * 4)
        *(float4*)(xs + idx) = *(const float4*)(x + (size_t)row0 * 64 + idx);
    __syncthreads();

    const float bias = b[lane];
    float acc[8];
    #pragma unroll
    for (int r = 0; r < 8; ++r) acc[r] = bias;

    const int rbase = wv * 8;
    const float* wrow = WL + lane * WSTRIDE;
    const float* xrow = xs + rbase * 64;
    #pragma unroll 1   // DO NOT unroll: keeps live set small (see header)
    for (int kk = 0; kk < 64; kk += 4) {
        const float2 w01 = *(const float2*)(wrow + kk);
        const float2 w23 = *(const float2*)(wrow + kk + 2);
        #pragma unroll
        for (int r = 0; r < 8; ++r) {
            const float4 xq = *(const float4*)(xrow + r * 64 + kk);
            acc[r] += xq.x * w01.x + xq.y * w01.y + xq.z * w23.x + xq.w * w23.y;
        }
    }

    // fused out-degree count: no __syncthreads after this point
    {
        const int e0 = blockIdx.x * 256 + tid;
        atomicAdd(&counts[ei[e0]], 1);
        atomicAdd(&counts[ei[e0 + GEMM_BLOCKS * 256]], 1);
    }

    const float asrc = a[(lane >> 3) * 16 + (lane & 7)];
    const float adst = a[(lane >> 3) * 16 + 8 + (lane & 7)];
    #pragma unroll
    for (int r = 0; r < 8; ++r) {
        const int row = row0 + rbase + r;
        const float v = acc[r];
        h16[(size_t)row * 64 + lane] = f2bf(v);
        float p = v * asrc, q = v * adst;
        p += __shfl_xor(p, 1);  q += __shfl_xor(q, 1);
        p += __shfl_xor(p, 2);  q += __shfl_xor(q, 2);
        p += __shfl_xor(p, 4);  q += __shfl_xor(q, 4);
        if ((lane & 7) == 0) {
            s_src[row * 8 + (lane >> 3)] = p;
            s_dst[row * 8 + (lane >> 3)] = q;
        }
    }
}

// ---------------------------------------------------------------------------
// Scan stage 1: per-tile (1024) exclusive scan + tile totals.
// ---------------------------------------------------------------------------
__global__ __launch_bounds__(1024) void k_scan1(
    const int* __restrict__ counts, int* __restrict__ row_ptr,
    int* __restrict__ blksum)
{
    __shared__ int wsum[16];
    const int tid = threadIdx.x, lane = tid & 63, wv = tid >> 6;
    const int i = blockIdx.x * SCAN_TILE + tid;
    int v = (i < N_NODES) ? counts[i] : 0;
    int sc = v;
    #pragma unroll
    for (int off = 1; off < 64; off <<= 1) {
        int t = __shfl_up(sc, off);
        if (lane >= off) sc += t;
    }
    if (lane == 63) wsum[wv] = sc;
    __syncthreads();
    if (tid < 16) {
        int ws = wsum[tid];
        #pragma unroll
        for (int off = 1; off < 16; off <<= 1) {
            int t = __shfl_up(ws, off);
            if (tid >= off) ws += t;
        }
        wsum[tid] = ws;
    }
    __syncthreads();
    const int pref = wv ? wsum[wv - 1] : 0;
    if (i < N_NODES) row_ptr[i] = pref + sc - v;   // tile-local exclusive
    if (tid == 0) blksum[blockIdx.x] = wsum[15];
}

// ---------------------------------------------------------------------------
// Scan stages 2+3 fused: redundant 98-element scan per block, add-back,
// cursor init.
// ---------------------------------------------------------------------------
__global__ __launch_bounds__(256) void k_scan23(
    int* __restrict__ row_ptr, const int* __restrict__ blksum,
    int* __restrict__ cursor)
{
    __shared__ int spref[N_TILES];
    const int tid = threadIdx.x;
    if (tid < 64) {
        int v0 = (tid < N_TILES) ? blksum[tid] : 0;
        int s0 = v0;
        #pragma unroll
        for (int off = 1; off < 64; off <<= 1) {
            int t = __shfl_up(s0, off);
            if (tid >= off) s0 += t;
        }
        if (tid < N_TILES) spref[tid] = s0 - v0;
        int carry = __shfl(s0, 63);
        int i2 = 64 + tid;
        int v1 = (i2 < N_TILES) ? blksum[i2] : 0;
        int s1 = v1;
        #pragma unroll
        for (int off = 1; off < 64; off <<= 1) {
            int t = __shfl_up(s1, off);
            if (tid >= off) s1 += t;
        }
        if (i2 < N_TILES) spref[i2] = carry + s1 - v1;
    }
    __syncthreads();
    const int i = blockIdx.x * 256 + tid;
    if (i < N_NODES) {
        int r = row_ptr[i] + spref[i >> 10];
        row_ptr[i] = r;
        cursor[i] = r;
    }
    if (i == 0) row_ptr[N_NODES] = N_EDGES;
}

// ---------------------------------------------------------------------------
// Fill + alpha: one THREAD per edge; scatter dst, compute 8-head softmax once.
// ---------------------------------------------------------------------------
__global__ __launch_bounds__(256) void k_fill_alpha(
    const int* __restrict__ ei, int* __restrict__ cursor,
    const float* __restrict__ s_src, const float* __restrict__ s_dst,
    int* __restrict__ dst_sorted, float* __restrict__ alpha8)
{
    const int e = blockIdx.x * 256 + threadIdx.x;
    if (e >= N_EDGES) return;
    const int src = ei[e];
    const int dst = ei[N_EDGES + e];
    const int slot = atomicAdd(&cursor[src], 1);
    dst_sorted[slot] = dst;

    const float4 a0 = *(const float4*)(s_src + (size_t)src * 8);
    const float4 a1 = *(const float4*)(s_src + (size_t)src * 8 + 4);
    const float4 b0 = *(const float4*)(s_dst + (size_t)dst * 8);
    const float4 b1 = *(const float4*)(s_dst + (size_t)dst * 8 + 4);
    float sc[8] = {a0.x + b0.x, a0.y + b0.y, a0.z + b0.z, a0.w + b0.w,
                   a1.x + b1.x, a1.y + b1.y, a1.z + b1.z, a1.w + b1.w};
    float m = -1e30f;
    #pragma unroll
    for (int h = 0; h < 8; ++h) {
        sc[h] = (sc[h] >= 0.f) ? sc[h] : 0.2f * sc[h];
        m = fmaxf(m, sc[h]);
    }
    float sum = 0.f;
    #pragma unroll
    for (int h = 0; h < 8; ++h) { sc[h] = __expf(sc[h] - m); sum += sc[h]; }
    const float inv = 1.f / sum;
    float4 o0 = make_float4(sc[0] * inv, sc[1] * inv, sc[2] * inv, sc[3] * inv);
    float4 o1 = make_float4(sc[4] * inv, sc[5] * inv, sc[6] * inv, sc[7] * inv);
    *(float4*)(alpha8 + (size_t)slot * 8)     = o0;
    *(float4*)(alpha8 + (size_t)slot * 8 + 4) = o1;
}

// ---------------------------------------------------------------------------
// Gather + epilogue: one wave per node; slim inner loop (alpha precomputed).
// ---------------------------------------------------------------------------
__global__ __launch_bounds__(256) void k_gather(
    const int* __restrict__ row_ptr, const int* __restrict__ dst_sorted,
    const float* __restrict__ alpha8, const unsigned short* __restrict__ h16,
    const float* __restrict__ x, const float* __restrict__ ln_scale,
    const float* __restrict__ ln_bias, float* __restrict__ out)
{
    const int i = blockIdx.x * 4 + (threadIdx.x >> 6);
    if (i >= N_NODES) return;
    const int lane = threadIdx.x & 63;
    const int head = lane >> 3;

    const int beg = row_ptr[i];
    const int end = row_ptr[i + 1];
    const float xres = x[(size_t)i * 64 + lane];

    float acc = 0.f;
    int e = beg;
    for (; e + 3 < end; e += 4) {
        const int d0 = dst_sorted[e];
        const int d1 = dst_sorted[e + 1];
        const int d2 = dst_sorted[e + 2];
        const int d3 = dst_sorted[e + 3];
        const float al0 = alpha8[(size_t)(e + 0) * 8 + head];
        const float al1 = alpha8[(size_t)(e + 1) * 8 + head];
        const float al2 = alpha8[(size_t)(e + 2) * 8 + head];
        const float al3 = alpha8[(size_t)(e + 3) * 8 + head];
        const float h0 = bf2f(h16[(size_t)d0 * 64 + lane]);
        const float h1 = bf2f(h16[(size_t)d1 * 64 + lane]);
        const float h2 = bf2f(h16[(size_t)d2 * 64 + lane]);
        const float h3 = bf2f(h16[(size_t)d3 * 64 + lane]);
        acc += al0 * h0 + al1 * h1 + al2 * h2 + al3 * h3;
    }
    for (; e < end; ++e)
        acc += alpha8[(size_t)e * 8 + head] *
               bf2f(h16[(size_t)dst_sorted[e] * 64 + lane]);

    // epilogue: residual + LayerNorm + L2 normalize
    float v = acc + xres;
    float s = v;
    #pragma unroll
    for (int off = 1; off < 64; off <<= 1) s += __shfl_xor(s, off);
    const float mu = s * (1.f / 64.f);
    const float d = v - mu;
    float vs = d * d;
    #pragma unroll
    for (int off = 1; off < 64; off <<= 1) vs += __shfl_xor(vs, off);
    const float var = vs * (1.f / 64.f);
    float y = d * rsqrtf(var + LN_EPS) * ln_scale[lane] + ln_bias[lane];
    float ss = y * y;
    #pragma unroll
    for (int off = 1; off < 64; off <<= 1) ss += __shfl_xor(ss, off);
    const float norm = sqrtf(ss);
    out[(size_t)i * 64 + lane] = y / fmaxf(norm, NORM_EPS);
}

// ---------------------------------------------------------------------------
extern "C" void kernel_launch(void* const* d_in, const int* in_sizes, int n_in,
                              void* d_out, int out_size, void* d_ws, size_t ws_size,
                              hipStream_t stream)
{
    const float* x        = (const float*)d_in[0];
    const int*   ei       = (const int*)d_in[1];
    const float* W        = (const float*)d_in[2];
    const float* b        = (const float*)d_in[3];
    const float* a        = (const float*)d_in[4];
    const float* ln_scale = (const float*)d_in[5];
    const float* ln_bias  = (const float*)d_in[6];
    float* out = (float*)d_out;

    char* ws = (char*)d_ws;
    size_t off = 0;
    auto alloc = [&](size_t bytes) {
        void* p = ws + off;
        off = (off + bytes + 255) & ~(size_t)255;
        return p;
    };
    unsigned short* h16 = (unsigned short*)alloc((size_t)N_NODES * 64 * 2);
    float* s_src      = (float*)alloc((size_t)N_NODES * 8 * 4);
    float* s_dst      = (float*)alloc((size_t)N_NODES * 8 * 4);
    int*   counts     = (int*)  alloc((size_t)N_NODES * 4);
    int*   row_ptr    = (int*)  alloc((size_t)(N_NODES + 1) * 4);
    int*   cursor     = (int*)  alloc((size_t)N_NODES * 4);
    int*   blksum     = (int*)  alloc((size_t)N_TILES * 4);
    int*   dst_sorted = (int*)  alloc((size_t)N_EDGES * 4);
    float* alpha8     = (float*)alloc((size_t)N_EDGES * 8 * 4);

    hipMemsetAsync(counts, 0, (size_t)N_NODES * 4, stream);

    k_gemm      <<<GEMM_BLOCKS, 256, 0, stream>>>(x, W, b, a, ei, counts,
                                                  h16, s_src, s_dst);
    k_scan1     <<<N_TILES, 1024, 0, stream>>>(counts, row_ptr, blksum);
    k_scan23    <<<(N_NODES + 255) / 256, 256, 0, stream>>>(row_ptr, blksum, cursor);
    k_fill_alpha<<<(N_EDGES + 255) / 256, 256, 0, stream>>>(ei, cursor, s_src, s_dst,
                                                            dst_sorted, alpha8);
    k_gather    <<<(N_NODES + 3) / 4,     256, 0, stream>>>(row_ptr, dst_sorted,
                                                            alpha8, h16, x,
                                                            ln_scale, ln_bias, out);
}